// Round 7
// baseline (178.221 us; speedup 1.0000x reference)
//
#include <hip/hip_runtime.h>
#include <math.h>

#define BATCH 4096
#define NC    8192
#define DIM   512
#define KEXP  5
#define NCAND 10

using bf16x8 = __attribute__((ext_vector_type(8))) short;
using f32x4  = __attribute__((ext_vector_type(4))) float;
typedef unsigned long long u64;

// module-scope device buffers (no hipMalloc; deterministic, rewritten every call)
__device__ unsigned short g_zbf[BATCH * DIM];   // 4 MB bf16(z)
__device__ unsigned short g_cbf[NC * DIM];      // 8 MB bf16(centers)
__device__ float g_z2[BATCH];
__device__ float g_c2[NC];

__device__ __forceinline__ unsigned short rtne_bf16(float f) {
  unsigned u = __float_as_uint(f);
  u += 0x7FFFu + ((u >> 16) & 1u);
  return (unsigned short)(u >> 16);
}

__device__ __forceinline__ void gload16(const void* g, void* l) {
  __builtin_amdgcn_global_load_lds(
      (const __attribute__((address_space(1))) void*)g,
      (__attribute__((address_space(3))) void*)l, 16, 0, 0);
}

// ---------------------------------------------------------------------------
// Kernel 0: f32 -> bf16 (RTN) one-shot conversion of z and centers.
// ---------------------------------------------------------------------------
__global__ __launch_bounds__(256) void convert_kernel(const float* __restrict__ z,
                                                      const float* __restrict__ c) {
  const size_t i = ((size_t)blockIdx.x * 256 + threadIdx.x) * 8;
  const size_t zn = (size_t)BATCH * DIM;
  const float* src;
  unsigned short* dst;
  size_t off;
  if (i < zn) { src = z; dst = g_zbf; off = i; }
  else        { src = c; dst = g_cbf; off = i - zn; }
  float4 a = *(const float4*)(src + off);
  float4 b = *(const float4*)(src + off + 4);
  uint4 o;
  o.x = (unsigned)rtne_bf16(a.x) | ((unsigned)rtne_bf16(a.y) << 16);
  o.y = (unsigned)rtne_bf16(a.z) | ((unsigned)rtne_bf16(a.w) << 16);
  o.z = (unsigned)rtne_bf16(b.x) | ((unsigned)rtne_bf16(b.y) << 16);
  o.w = (unsigned)rtne_bf16(b.z) | ((unsigned)rtne_bf16(b.w) << 16);
  *(uint4*)(dst + off) = o;
}

// ---------------------------------------------------------------------------
// Kernel 1: row squared-norms, f64 accumulation.
// ---------------------------------------------------------------------------
__global__ __launch_bounds__(128) void norms_kernel(const float* __restrict__ z,
                                                    const float* __restrict__ c) {
  int row = blockIdx.x;
  const float* src;
  float* dst;
  if (row < BATCH) { src = z + (size_t)row * DIM; dst = g_z2 + row; }
  else             { src = c + (size_t)(row - BATCH) * DIM; dst = g_c2 + (row - BATCH); }
  int t = threadIdx.x;
  float4 v = ((const float4*)src)[t];
  double acc = (double)v.x * v.x + (double)v.y * v.y + (double)v.z * v.z + (double)v.w * v.w;
#pragma unroll
  for (int off = 32; off > 0; off >>= 1) acc += __shfl_down(acc, off);
  __shared__ double wsum[2];
  if ((t & 63) == 0) wsum[t >> 6] = acc;
  __syncthreads();
  if (t == 0) *dst = (float)(wsum[0] + wsum[1]);
}

// ---------------------------------------------------------------------------
// Kernel 2: attractions GEMM, BK=32 double-buffered 2-phase pipeline.
// - STAGE(s+1) issued BEFORE compute(s); one vmcnt-draining barrier/step.
// - Column-major tile walk within each XCD's 4-tile-row strip (B L2 reuse).
// - Swapped operands mfma(fb, fa): C reg-dim runs along att COLUMNS ->
//   epilogue uses global_store_dwordx4.
// - LDS [128][32] bf16 rows (64 B), XOR swizzle on 16B granules:
//   read granule (lane>>4) ^ (((lane&15)>>1)&3); stage source granule
//   (lane&3) ^ ((lane>>3)&3). Max 2-way bank aliasing (free).
// ---------------------------------------------------------------------------
#define BM  128
#define BN  128

__global__ __launch_bounds__(256) void attr_bf16(const float* __restrict__ mus,
                                                 float* __restrict__ att) {
  __shared__ __align__(16) unsigned short Ab[2][BM * 32];  // 8 KB each
  __shared__ __align__(16) unsigned short Bb[2][BM * 32];

  const int tid  = threadIdx.x;
  const int lane = tid & 63;
  const int wv   = tid >> 6;
  const int wm   = wv >> 1;
  const int wn   = wv & 1;

  // XCD strip (4 tile-rows), column-major walk within the strip
  const int flat = blockIdx.x;          // 2048 blocks
  const int xcd  = flat & 7;
  const int t    = flat >> 3;           // 0..255
  const int row0 = (xcd * 4 + (t & 3)) * BM;
  const int col0 = (t >> 2) * BN;

  const unsigned short* Ag = g_zbf + (size_t)row0 * DIM;
  const unsigned short* Bg = g_cbf + (size_t)col0 * DIM;

  // staging geometry: per inst, wave wv covers rows inst*64 + wv*16 .. +16
  const int srow = wv * 16 + (lane >> 2);              // + inst*64
  const int sg   = (lane & 3) ^ ((lane >> 3) & 3);     // source k-granule

  // compute-side: granule per thread (constant)
  const int q  = lane >> 4;
  const int gq = q ^ (((lane & 15) >> 1) & 3);
  const int l15 = lane & 15;

  f32x4 acc[4][4] = {};   // acc[j][i]: j = B frag (att cols), i = A frag (rows)

#define STAGE(S, B)                                                         \
  {                                                                         \
    const int k0_ = (S) * 32;                                               \
    _Pragma("unroll")                                                       \
    for (int inst = 0; inst < 2; ++inst) {                                  \
      const int r_ = inst * 64 + srow;                                      \
      gload16(Ag + (size_t)r_ * DIM + k0_ + sg * 8,                         \
              &Ab[B][(inst * 64 + wv * 16) * 32]);                          \
      gload16(Bg + (size_t)r_ * DIM + k0_ + sg * 8,                         \
              &Bb[B][(inst * 64 + wv * 16) * 32]);                          \
    }                                                                       \
  }

  STAGE(0, 0);
  __syncthreads();

  for (int s = 0; s < 16; ++s) {
    const int cur = s & 1;
    if (s < 15) STAGE(s + 1, cur ^ 1);

    bf16x8 fa[4], fb[4];
#pragma unroll
    for (int i = 0; i < 4; ++i) {
      const int r = wm * 64 + i * 16 + l15;
      fa[i] = *(const bf16x8*)((const char*)&Ab[cur][0] + r * 64 + gq * 16);
    }
#pragma unroll
    for (int j = 0; j < 4; ++j) {
      const int r = wn * 64 + j * 16 + l15;
      fb[j] = *(const bf16x8*)((const char*)&Bb[cur][0] + r * 64 + gq * 16);
    }
#pragma unroll
    for (int j = 0; j < 4; ++j)
#pragma unroll
      for (int i = 0; i < 4; ++i)
        acc[j][i] = __builtin_amdgcn_mfma_f32_16x16x32_bf16(fb[j], fa[i], acc[j][i], 0, 0, 0);
    __syncthreads();
  }

  // epilogue: row = A side (lane&15), cols = reg-dim -> dwordx4 stores
#pragma unroll
  for (int i = 0; i < 4; ++i) {
    const int ar = row0 + wm * 64 + i * 16 + l15;
    const float zz = g_z2[ar];
    float* dst = att + (size_t)ar * NC;
#pragma unroll
    for (int j = 0; j < 4; ++j) {
      const int gc0 = col0 + wn * 64 + j * 16 + q * 4;
      const float4 cc = *(const float4*)&g_c2[gc0];
      const float4 mu = *(const float4*)&mus[gc0];
      const float ccv[4] = {cc.x, cc.y, cc.z, cc.w};
      const float muv[4] = {mu.x, mu.y, mu.z, mu.w};
      float o[4];
#pragma unroll
      for (int r = 0; r < 4; ++r) {
        float tt  = __fadd_rn(zz, ccv[r]);
        float sq  = __fsub_rn(tt, __fmul_rn(2.0f, acc[j][i][r]));
        float d   = sqrtf(fmaxf(sq, 0.0f));
        float den = __fadd_rn(__fmul_rn(d, d), 1e-6f);
        o[r] = __fdiv_rn(muv[r], den);
      }
      *(float4*)(dst + gc0) = *(const float4*)o;
    }
  }
#undef STAGE
}

// ---------------------------------------------------------------------------
// Kernel 3: wave-per-row top-NCAND via packed-key pop-lists (unchanged).
// ---------------------------------------------------------------------------
__global__ __launch_bounds__(256, 4) void topk_kernel(const float* __restrict__ att,
                                                      const float* __restrict__ z,
                                                      const float* __restrict__ centers,
                                                      const float* __restrict__ mus,
                                                      float* __restrict__ out) {
  __shared__ int selLds[4][16];
  const int lane = threadIdx.x & 63;
  const int wv   = threadIdx.x >> 6;
  const int row  = blockIdx.x * 4 + wv;
  const float4* arow4 = (const float4*)(att + (size_t)row * NC);

  u64 k[8][4];
#pragma unroll
  for (int c = 0; c < 8; ++c) {
#pragma unroll
    for (int j = 0; j < 4; ++j) k[c][j] = 0ull;
#pragma unroll
    for (int qq = 0; qq < 4; ++qq) {
      float4 v4 = arow4[c * 256 + qq * 64 + lane];
      const unsigned ib = (unsigned)(c * 1024 + qq * 256 + lane * 4);
      const float vv[4] = {v4.x, v4.y, v4.z, v4.w};
#pragma unroll
      for (int e = 0; e < 4; ++e) {
        u64 nk = ((u64)__float_as_uint(vv[e]) << 32) | (u64)(0xFFFFFFFFu - (ib + e));
        bool g0 = nk > k[c][0], g1 = nk > k[c][1], g2 = nk > k[c][2], g3 = nk > k[c][3];
        u64 t0 = k[c][0], t1 = k[c][1], t2 = k[c][2];
        k[c][0] = g0 ? nk : k[c][0];
        k[c][1] = g0 ? t0 : (g1 ? nk : k[c][1]);
        k[c][2] = g1 ? t1 : (g2 ? nk : k[c][2]);
        k[c][3] = g2 ? t2 : (g3 ? nk : k[c][3]);
      }
    }
  }

  for (int it = 0; it < NCAND; ++it) {
    u64 b = k[0][0];
#pragma unroll
    for (int c = 1; c < 8; ++c) b = (k[c][0] > b) ? k[c][0] : b;
#pragma unroll
    for (int off = 32; off > 0; off >>= 1) {
      u64 o = __shfl_xor(b, off);
      b = (o > b) ? o : b;
    }
    if (lane == 0) selLds[wv][it] = (int)(0xFFFFFFFFu - (unsigned)(b & 0xFFFFFFFFu));
#pragma unroll
    for (int c = 0; c < 8; ++c) {
      bool hit = (k[c][0] == b);
      k[c][0] = hit ? k[c][1] : k[c][0];
      k[c][1] = hit ? k[c][2] : k[c][1];
      k[c][2] = hit ? k[c][3] : k[c][2];
      k[c][3] = hit ? 0ull    : k[c][3];
    }
  }

  const float* zrow = z + (size_t)row * DIM;
  const int d0 = lane * 8;
  const float4 za = *(const float4*)(zrow + d0);
  const float4 zb = *(const float4*)(zrow + d0 + 4);
  const float myz2 = g_z2[row];

  double p[NCAND];
  int cidx[NCAND];
#pragma unroll
  for (int c = 0; c < NCAND; ++c) {
    cidx[c] = selLds[wv][c];
    const float* cp = centers + (size_t)cidx[c] * DIM + d0;
    float4 ca = *(const float4*)(cp);
    float4 cb = *(const float4*)(cp + 4);
    p[c] = (double)za.x * ca.x + (double)za.y * ca.y +
           (double)za.z * ca.z + (double)za.w * ca.w +
           (double)zb.x * cb.x + (double)zb.y * cb.y +
           (double)zb.z * cb.z + (double)zb.w * cb.w;
  }
#pragma unroll
  for (int off = 32; off > 0; off >>= 1) {
#pragma unroll
    for (int c = 0; c < NCAND; ++c) p[c] += __shfl_xor(p[c], off);
  }

  float exv[NCAND];
#pragma unroll
  for (int c = 0; c < NCAND; ++c) {
    const int ci = cidx[c];
    float dotf = (float)p[c];
    float t   = __fadd_rn(myz2, g_c2[ci]);
    float sq  = __fsub_rn(t, __fmul_rn(2.0f, dotf));
    float d   = sqrtf(fmaxf(sq, 0.0f));
    float den = __fadd_rn(__fmul_rn(d, d), 1e-6f);
    exv[c] = __fdiv_rn(mus[ci], den);
  }

  unsigned used = 0;
  float tv[KEXP]; int tix[KEXP];
#pragma unroll
  for (int s = 0; s < KEXP; ++s) {
    float bv = -INFINITY; int bi = 0x7FFFFFFF; int bc = 0;
#pragma unroll
    for (int c = 0; c < NCAND; ++c) {
      bool ok = (used & (1u << c)) == 0;
      if (ok && (exv[c] > bv || (exv[c] == bv && cidx[c] < bi))) {
        bv = exv[c]; bi = cidx[c]; bc = c;
      }
    }
    used |= (1u << bc);
    tv[s] = bv; tix[s] = bi;
  }

  float m = tv[0];
  float w[KEXP];
  float s = 0.0f;
#pragma unroll
  for (int kk = 0; kk < KEXP; ++kk) { w[kk] = expf(tv[kk] - m); s += w[kk]; }
#pragma unroll
  for (int kk = 0; kk < KEXP; ++kk) w[kk] /= s;

  float comb[8] = {0, 0, 0, 0, 0, 0, 0, 0};
#pragma unroll
  for (int kk = 0; kk < KEXP; ++kk) {
    const float* cp = centers + (size_t)tix[kk] * DIM + d0;
    float4 a = *(const float4*)(cp);
    float4 bq = *(const float4*)(cp + 4);
    comb[0] += w[kk] * a.x;  comb[1] += w[kk] * a.y;
    comb[2] += w[kk] * a.z;  comb[3] += w[kk] * a.w;
    comb[4] += w[kk] * bq.x; comb[5] += w[kk] * bq.y;
    comb[6] += w[kk] * bq.z; comb[7] += w[kk] * bq.w;
  }
  const float zv[8] = {za.x, za.y, za.z, za.w, zb.x, zb.y, zb.z, zb.w};
  float o[8];
#pragma unroll
  for (int e = 0; e < 8; ++e)
    o[e] = __fadd_rn(__fmul_rn(0.7f, zv[e]), __fmul_rn(0.3f, comb[e]));
  *(float4*)(out + (size_t)row * DIM + d0)     = *(float4*)&o[0];
  *(float4*)(out + (size_t)row * DIM + d0 + 4) = *(float4*)&o[4];
}

// ---------------------------------------------------------------------------
extern "C" void kernel_launch(void* const* d_in, const int* in_sizes, int n_in,
                              void* d_out, int out_size, void* d_ws, size_t ws_size,
                              hipStream_t stream) {
  const float* z       = (const float*)d_in[0];
  const float* centers = (const float*)d_in[1];
  const float* mus     = (const float*)d_in[2];
  float* out      = (float*)d_out;
  float* expanded = out;
  float* att      = out + (size_t)BATCH * DIM;

  convert_kernel<<<(BATCH + NC) * DIM / (256 * 8), 256, 0, stream>>>(z, centers);
  norms_kernel<<<BATCH + NC, 128, 0, stream>>>(z, centers);
  attr_bf16<<<(BATCH / BM) * (NC / BN), 256, 0, stream>>>(mus, att);
  topk_kernel<<<BATCH / 4, 256, 0, stream>>>(att, z, centers, mus, expanded);
}